// Round 1
// baseline (148.046 us; speedup 1.0000x reference)
//
#include <hip/hip_runtime.h>

// ---------------------------------------------------------------------------
// RMSNormSparse: out = weight * (mask?x:0) * rsqrt(mean((mask?x:0)^2) + eps)
// B=4, S=4096, D=4096, fp32 in/out. Memory-bound streaming kernel.
//
// The bool mask's device layout is ambiguous (uint8 vs int32 vs float32
// depending on harness conversion). detect_mask() inspects the first 1024
// bytes once per call and writes a flag to d_ws:
//   0 = uint8 bytes (0/1), 1 = int32 (0/1), 2 = float32 (0.0/1.0)
// Rationale: float32 1.0f has byte 0x3f at offset 3 mod 4; int32 0/1 has
// all-zero bytes at offsets 1..3 mod 4; uint8 random 0/1 has ~half nonzero
// bytes at every offset (P[misdetect as int32] = 2^-768).
// ---------------------------------------------------------------------------

#define EPS_RMS 1e-5f

__global__ void detect_mask_kernel(const unsigned char* __restrict__ mb,
                                   int* __restrict__ flag) {
    __shared__ int nz_off;  // any nonzero byte at offset%4 != 0
    __shared__ int f3;      // any 0x3f byte at offset%4 == 3  -> float32
    if (threadIdx.x == 0) { nz_off = 0; f3 = 0; }
    __syncthreads();
    unsigned int i = threadIdx.x * 4u;  // 256 threads x 4 bytes = 1024 bytes
    unsigned char b1 = mb[i + 1], b2 = mb[i + 2], b3 = mb[i + 3];
    if ((b1 | b2 | b3) != 0) atomicOr(&nz_off, 1);
    if (b3 == 0x3fu) atomicOr(&f3, 1);
    __syncthreads();
    if (threadIdx.x == 0) {
        *flag = f3 ? 2 : (nz_off ? 0 : 1);
    }
}

// Fast path: D == 4096, one 256-thread block per row, 16 floats/thread.
__global__ __launch_bounds__(256) void rmsnorm_sparse_4096(
    const float* __restrict__ x,
    const void* __restrict__ mask,
    const float* __restrict__ weight,
    float* __restrict__ out,
    const int* __restrict__ flag_p) {
    const int D = 4096;
    const int row = blockIdx.x;
    const int t = threadIdx.x;
    const int flag = *flag_p;  // block-uniform
    const size_t base = (size_t)row * (size_t)D;

    const float4* __restrict__ x4 = (const float4*)(x + base);
    float4* __restrict__ o4 = (float4*)(out + base);
    const float4* __restrict__ w4 = (const float4*)weight;

    float4 v[4];

    if (flag == 0) {
        const uchar4* m4 = (const uchar4*)((const unsigned char*)mask + base);
#pragma unroll
        for (int i = 0; i < 4; ++i) {
            const int idx = t + i * 256;
            float4 xv = x4[idx];
            uchar4 u = m4[idx];
            xv.x = u.x ? xv.x : 0.f;
            xv.y = u.y ? xv.y : 0.f;
            xv.z = u.z ? xv.z : 0.f;
            xv.w = u.w ? xv.w : 0.f;
            v[i] = xv;
        }
    } else if (flag == 1) {
        const int4* m4 = (const int4*)((const int*)mask + base);
#pragma unroll
        for (int i = 0; i < 4; ++i) {
            const int idx = t + i * 256;
            float4 xv = x4[idx];
            int4 u = m4[idx];
            xv.x = u.x ? xv.x : 0.f;
            xv.y = u.y ? xv.y : 0.f;
            xv.z = u.z ? xv.z : 0.f;
            xv.w = u.w ? xv.w : 0.f;
            v[i] = xv;
        }
    } else {
        const float4* m4 = (const float4*)((const float*)mask + base);
#pragma unroll
        for (int i = 0; i < 4; ++i) {
            const int idx = t + i * 256;
            float4 xv = x4[idx];
            float4 u = m4[idx];
            xv.x = (u.x != 0.f) ? xv.x : 0.f;
            xv.y = (u.y != 0.f) ? xv.y : 0.f;
            xv.z = (u.z != 0.f) ? xv.z : 0.f;
            xv.w = (u.w != 0.f) ? xv.w : 0.f;
            v[i] = xv;
        }
    }

    // Sum of squares: per-thread, then wave64 shuffle, then cross-wave LDS.
    float s = 0.f;
#pragma unroll
    for (int i = 0; i < 4; ++i) {
        s += v[i].x * v[i].x + v[i].y * v[i].y + v[i].z * v[i].z +
             v[i].w * v[i].w;
    }
#pragma unroll
    for (int off = 32; off > 0; off >>= 1) s += __shfl_down(s, off);

    __shared__ float ws[4];
    const int lane = t & 63;
    const int wave = t >> 6;
    if (lane == 0) ws[wave] = s;
    __syncthreads();
    const float total = ws[0] + ws[1] + ws[2] + ws[3];
    const float scale = rsqrtf(total * (1.0f / (float)D) + EPS_RMS);

#pragma unroll
    for (int i = 0; i < 4; ++i) {
        const int idx = t + i * 256;
        float4 w = w4[idx];
        float4 o;
        o.x = v[i].x * scale * w.x;
        o.y = v[i].y * scale * w.y;
        o.z = v[i].z * scale * w.z;
        o.w = v[i].w * scale * w.w;
        o4[idx] = o;
    }
}

// Generic fallback for D != 4096 (scalar, two-phase; correctness only).
__global__ void rmsnorm_sparse_generic(const float* __restrict__ x,
                                       const void* __restrict__ mask,
                                       const float* __restrict__ weight,
                                       float* __restrict__ out,
                                       const int* __restrict__ flag_p, int D) {
    const int row = blockIdx.x;
    const int t = threadIdx.x;
    const int flag = *flag_p;
    const size_t base = (size_t)row * (size_t)D;

    float s = 0.f;
    for (int d = t; d < D; d += blockDim.x) {
        float xv = x[base + d];
        bool m;
        if (flag == 0)
            m = ((const unsigned char*)mask)[base + d] != 0;
        else if (flag == 1)
            m = ((const int*)mask)[base + d] != 0;
        else
            m = ((const float*)mask)[base + d] != 0.f;
        float xm = m ? xv : 0.f;
        s += xm * xm;
    }
#pragma unroll
    for (int off = 32; off > 0; off >>= 1) s += __shfl_down(s, off);
    __shared__ float ws[16];
    const int lane = t & 63;
    const int wave = t >> 6;
    if (lane == 0) ws[wave] = s;
    __syncthreads();
    float total = 0.f;
    const int nw = (blockDim.x + 63) / 64;
    for (int i = 0; i < nw; ++i) total += ws[i];
    const float scale = rsqrtf(total / (float)D + EPS_RMS);

    for (int d = t; d < D; d += blockDim.x) {
        float xv = x[base + d];
        bool m;
        if (flag == 0)
            m = ((const unsigned char*)mask)[base + d] != 0;
        else if (flag == 1)
            m = ((const int*)mask)[base + d] != 0;
        else
            m = ((const float*)mask)[base + d] != 0.f;
        float xm = m ? xv : 0.f;
        out[base + d] = weight[d] * xm * scale;
    }
}

extern "C" void kernel_launch(void* const* d_in, const int* in_sizes, int n_in,
                              void* d_out, int out_size, void* d_ws,
                              size_t ws_size, hipStream_t stream) {
    const float* x = (const float*)d_in[0];
    const void* mask = d_in[1];
    const float* weight = (const float*)d_in[2];
    float* out = (float*)d_out;

    const int D = in_sizes[2];            // weight length
    const int rows = in_sizes[0] / D;     // B*S

    int* flag = (int*)d_ws;
    detect_mask_kernel<<<1, 256, 0, stream>>>((const unsigned char*)mask, flag);

    if (D == 4096) {
        rmsnorm_sparse_4096<<<rows, 256, 0, stream>>>(x, mask, weight, out,
                                                      flag);
    } else {
        rmsnorm_sparse_generic<<<rows, 256, 0, stream>>>(x, mask, weight, out,
                                                         flag, D);
    }
}